// Round 16
// baseline (1757.809 us; speedup 1.0000x reference)
//
#include <hip/hip_runtime.h>
#include <stdint.h>

// RNNModel: h_{t+1} = hardtanh(x_t @ W_in^T + h_t @ W_h^T), out = h_T @ W_out^T
// B=1024 T=2048 D=13 H=128 O=2, fp32 in/out.
//
// Round 16 = r13 (best, 1211us: rotation self-fragment, uniform flow) with the
// in-loop s_barrier REPLACED by per-wave monotone LDS flags:
//  - flag[w] = t, written after lgkmcnt(0) drains wave w's h-write. A wave's
//    flag certifies BOTH "my h_t slice is in LDS" and "my reads of the buffer
//    about to be overwritten are done" (reads precede write by dataflow).
//  - Step: x-conv + 6 x-MFMAs + x-prefetch BEFORE the poll (overlaps straggler
//    tails); poll 3 flags >= t-1; 6 b128 reads; 6 self-MFMAs (read-latency
//    cover); 18 LDS MFMAs; epilogue; write; lgkm; flag. No s_barrier, no convoy.
//  - r10/r13 fit showed MFMA issue = 19.4cy/MFMA (at rate); the ~1020cy/step
//    residual is the serial chain + barrier convoy — this attacks the latter.
// Arithmetic is bit-identical to r13 (absmax must stay 0.0078125).

#define RNN_B 1024
#define RNN_T 2048
#define RNN_D 13
#define RNN_H 128
#define RNN_O 2

#define NB 16
#define NWAVE 4
#define NTHR (NWAVE * 64)
#define ROWS 136              // shorts per batch row: 128 data + 8 pad (17 quads)

using f32x4 = __attribute__((ext_vector_type(4))) float;
using v8s   = __attribute__((ext_vector_type(8))) short;

__device__ __forceinline__ short f2bf(float f) {           // setup only
    union { float f; uint32_t u; } c; c.f = f;
    uint32_t u = c.u + 0x7fffu + ((c.u >> 16) & 1u);
    return (short)(u >> 16);
}
__device__ __forceinline__ float bf2fs(short s) {
    union { uint32_t u; float f; } c; c.u = ((uint32_t)(uint16_t)s) << 16;
    return c.f;
}
__device__ __forceinline__ float bitf(uint32_t u) {
    union { uint32_t u; float f; } c; c.u = u; return c.f;
}
__device__ __forceinline__ uint32_t cvtpk(float a, float b) {  // [bf16(b)|bf16(a)]
    uint32_t r;
    asm("v_cvt_pk_bf16_f32 %0, %1, %2" : "=v"(r) : "v"(a), "v"(b));
    return r;
}
__device__ __forceinline__ v8s pack4(uint32_t a, uint32_t b, uint32_t c, uint32_t d) {
    union { uint32_t u[4]; v8s s; } z;
    z.u[0] = a; z.u[1] = b; z.u[2] = c; z.u[3] = d; return z.s;
}
__device__ __forceinline__ float clamp1(float v) {
    return __builtin_amdgcn_fmed3f(v, -1.0f, 1.0f);
}

#define MFMA(a, b, c) __builtin_amdgcn_mfma_f32_16x16x32_bf16((a), (b), (c), 0, 0, 0)

// One step, uniform for all waves; flag-synced (no s_barrier).
#define STEP(CUR, NXT, X0, X1, X2, X3, TPF, TCUR)                                \
  do {                                                                           \
    /* 1) x fragments (VALU-only; runs while stragglers finish t-1) */           \
    float m0 = X0, m1 = X1, m2 = X2, m3 = X3;                                    \
    if (g == 3) { m1 = 0.0f; m2 = 0.0f; m3 = 0.0f; }                             \
    uint32_t xh01 = cvtpk(m0, m1), xh23 = cvtpk(m2, m3);                         \
    float q0 = m0 - bitf(xh01 << 16);                                            \
    float q1 = m1 - bitf(xh01 & 0xffff0000u);                                    \
    float q2 = m2 - bitf(xh23 << 16);                                            \
    float q3 = m3 - bitf(xh23 & 0xffff0000u);                                    \
    uint32_t xl01 = cvtpk(q0, q1), xl23 = cvtpk(q2, q3);                         \
    v8s xh = pack4(xh01, xh23, 0u, 0u);                                          \
    v8s xl = pack4(xl01, xl23, 0u, 0u);                                          \
    /* 2) x-term MFMAs (reg-only) seed accumulators */                           \
    f32x4 Z = {0.f, 0.f, 0.f, 0.f};                                              \
    f32x4 A1 = MFMA(whiA[4], xh, Z);                                             \
    f32x4 B1 = MFMA(whiB[4], xh, Z);                                             \
    f32x4 A2 = MFMA(whiA[4], xl, Z);                                             \
    f32x4 B2 = MFMA(whiB[4], xl, Z);                                             \
    f32x4 A3 = MFMA(wloA[4], xh, Z);                                             \
    f32x4 B3 = MFMA(wloB[4], xh, Z);                                             \
    /* 3) x prefetch two steps ahead (vmcnt, never drained in-loop) */           \
    if ((TPF) < RNN_T) {                                                         \
      const float* xp = xrow + (size_t)(TPF) * RNN_D;                            \
      X0 = xp[d0]; X1 = xp[d1]; X2 = xp[d2]; X3 = xp[d3];                        \
    }                                                                            \
    /* 4) poll the 3 other waves' flags (>= TCUR-1) */                           \
    {                                                                            \
      volatile int* vf = hflag;                                                  \
      const int need = (TCUR) - 1;                                               \
      while (vf[wq1] < need) {}                                                  \
      while (vf[wq2] < need) {}                                                  \
      while (vf[wq3] < need) {}                                                  \
      asm volatile("" ::: "memory");                                             \
    }                                                                            \
    /* 5) issue reads for q=1..3 (safe now) */                                   \
    v8s bh1 = *(const v8s*)&Hhi[CUR][n][ktq1 + g8];                              \
    v8s bl1 = *(const v8s*)&Hlo[CUR][n][ktq1 + g8];                              \
    v8s bh2 = *(const v8s*)&Hhi[CUR][n][ktq2 + g8];                              \
    v8s bl2 = *(const v8s*)&Hlo[CUR][n][ktq2 + g8];                              \
    v8s bh3 = *(const v8s*)&Hhi[CUR][n][ktq3 + g8];                              \
    v8s bl3 = *(const v8s*)&Hlo[CUR][n][ktq3 + g8];                              \
    /* 6) self-term MFMAs (reg-only; cover read latency) */                      \
    A1 = MFMA(whiA[0], selfBh, A1);                                              \
    B1 = MFMA(whiB[0], selfBh, B1);                                              \
    A2 = MFMA(whiA[0], selfBl, A2);                                              \
    B2 = MFMA(whiB[0], selfBl, B2);                                              \
    A3 = MFMA(wloA[0], selfBh, A3);                                              \
    B3 = MFMA(wloB[0], selfBh, B3);                                              \
    /* 7) LDS-dependent MFMAs as fragments arrive */                             \
    A1 = MFMA(whiA[1], bh1, A1);                                                 \
    B1 = MFMA(whiB[1], bh1, B1);                                                 \
    A2 = MFMA(whiA[1], bl1, A2);                                                 \
    B2 = MFMA(whiB[1], bl1, B2);                                                 \
    A3 = MFMA(wloA[1], bh1, A3);                                                 \
    B3 = MFMA(wloB[1], bh1, B3);                                                 \
    A1 = MFMA(whiA[2], bh2, A1);                                                 \
    B1 = MFMA(whiB[2], bh2, B1);                                                 \
    A2 = MFMA(whiA[2], bl2, A2);                                                 \
    B2 = MFMA(whiB[2], bl2, B2);                                                 \
    A3 = MFMA(wloA[2], bh2, A3);                                                 \
    B3 = MFMA(wloB[2], bh2, B3);                                                 \
    A1 = MFMA(whiA[3], bh3, A1);                                                 \
    A2 = MFMA(whiA[3], bl3, A2);                                                 \
    A3 = MFMA(wloA[3], bh3, A3);                                                 \
    /* 8) A epilogue (overlaps B's last MFMA group) + A writes */                \
    float v0 = clamp1(A1[0] + A2[0] + A3[0]);                                    \
    float v1 = clamp1(A1[1] + A2[1] + A3[1]);                                    \
    float v2 = clamp1(A1[2] + A2[2] + A3[2]);                                    \
    float v3 = clamp1(A1[3] + A2[3] + A3[3]);                                    \
    B1 = MFMA(whiB[3], bh3, B1);                                                 \
    B2 = MFMA(whiB[3], bl3, B2);                                                 \
    B3 = MFMA(wloB[3], bh3, B3);                                                 \
    uint32_t h01A = cvtpk(v0, v1), h23A = cvtpk(v2, v3);                         \
    float p0 = v0 - bitf(h01A << 16);                                            \
    float p1 = v1 - bitf(h01A & 0xffff0000u);                                    \
    float p2 = v2 - bitf(h23A << 16);                                            \
    float p3 = v3 - bitf(h23A & 0xffff0000u);                                    \
    uint32_t l01A = cvtpk(p0, p1), l23A = cvtpk(p2, p3);                         \
    {                                                                            \
      int2 wv; wv.x = (int)h01A; wv.y = (int)h23A;                               \
      *(int2*)&Hhi[NXT][n][wbase + g8] = wv;                                     \
      wv.x = (int)l01A; wv.y = (int)l23A;                                        \
      *(int2*)&Hlo[NXT][n][wbase + g8] = wv;                                     \
    }                                                                            \
    /* 9) B epilogue; combined fragments = next selfB; B writes */               \
    {                                                                            \
      float w0 = clamp1(B1[0] + B2[0] + B3[0]);                                  \
      float w1 = clamp1(B1[1] + B2[1] + B3[1]);                                  \
      float w2 = clamp1(B1[2] + B2[2] + B3[2]);                                  \
      float w3 = clamp1(B1[3] + B2[3] + B3[3]);                                  \
      uint32_t h01B = cvtpk(w0, w1), h23B = cvtpk(w2, w3);                       \
      float r0 = w0 - bitf(h01B << 16);                                          \
      float r1 = w1 - bitf(h01B & 0xffff0000u);                                  \
      float r2 = w2 - bitf(h23B << 16);                                          \
      float r3 = w3 - bitf(h23B & 0xffff0000u);                                  \
      uint32_t l01B = cvtpk(r0, r1), l23B = cvtpk(r2, r3);                       \
      selfBh = pack4(h01A, h23A, h01B, h23B);                                    \
      selfBl = pack4(l01A, l23A, l01B, l23B);                                    \
      int2 wv; wv.x = (int)h01B; wv.y = (int)h23B;                               \
      *(int2*)&Hhi[NXT][n][wbase + g8 + 4] = wv;                                 \
      wv.x = (int)l01B; wv.y = (int)l23B;                                        \
      *(int2*)&Hlo[NXT][n][wbase + g8 + 4] = wv;                                 \
    }                                                                            \
    /* 10) publish: drain LDS writes, then set my flag */                        \
    asm volatile("s_waitcnt lgkmcnt(0)" ::: "memory");                           \
    if (lane == 0) { volatile int* vf = hflag; vf[wid] = (TCUR); }               \
  } while (0)

__global__ __launch_bounds__(NTHR, 1) void rnn_mfma16_kernel(
    const float* __restrict__ xs,     // [B, T, D]
    const float* __restrict__ W_in,   // [H, D]
    const float* __restrict__ W_h,    // [H, H]
    const float* __restrict__ W_out,  // [O, H]
    float* __restrict__ out)          // [B, O]
{
    __shared__ __align__(16) short Hhi[2][NB][ROWS];
    __shared__ __align__(16) short Hlo[2][NB][ROWS];
    __shared__ int hflag[NWAVE];

    const int tid  = threadIdx.x;
    const int lane = tid & 63;
    const int wid  = tid >> 6;       // wave 0..3; self kt = wid
    const int n    = lane & 15;      // batch col / A-row within tile
    const int g    = lane >> 4;      // k-group 0..3
    const int g8   = g * 8;
    const int wbase = 32 * wid;      // write base: pos = 32*wid + 8g + 4*mi
    const int b0   = blockIdx.x * NB;

    // rotated kt indices/offsets for q=1..3 (runtime-uniform)
    const int wq1 = (wid + 1) & 3, wq2 = (wid + 2) & 3, wq3 = (wid + 3) & 3;
    const int ktq1 = wq1 * 32, ktq2 = wq2 * 32, ktq3 = wq3 * 32;

    // clamped x element indices for this lane (d = 4g+j, clamped into [0,12])
    const int d0 = (4 * g + 0 > 12) ? 12 : 4 * g + 0;
    const int d1 = (4 * g + 1 > 12) ? 12 : 4 * g + 1;
    const int d2 = (4 * g + 2 > 12) ? 12 : 4 * g + 2;
    const int d3 = (4 * g + 3 > 12) ? 12 : 4 * g + 3;

    // ---- A fragments, ROTATED: wA[q] <-> kt=(wid+q)&3; index 4 = x tile ----
    v8s whiA[5], wloA[5], whiB[5], wloB[5];
    #pragma unroll
    for (int mi = 0; mi < 2; ++mi) {
        const int row = 16 * (wid * 2 + mi) + n;
        #pragma unroll
        for (int q = 0; q < 4; ++q) {
            const int kt = (wid + q) & 3;          // runtime; addresses only
            v8s h8, l8;
            #pragma unroll
            for (int j = 0; j < 4; ++j) {
                const float w1 = W_h[row * RNN_H + 32 * kt + 4 * g + j];
                const float w2 = W_h[row * RNN_H + 32 * kt + 16 + 4 * g + j];
                const short h1 = f2bf(w1);
                const short h2 = f2bf(w2);
                h8[j] = h1; h8[4 + j] = h2;
                l8[j] = f2bf(w1 - bf2fs(h1));
                l8[4 + j] = f2bf(w2 - bf2fs(h2));
            }
            if (mi == 0) { whiA[q] = h8; wloA[q] = l8; }
            else         { whiB[q] = h8; wloB[q] = l8; }
        }
        {   // x tile (index 4)
            v8s h8, l8;
            #pragma unroll
            for (int j = 0; j < 4; ++j) {
                const int kx = 4 * g + j;
                const float w1 = (kx < RNN_D) ? W_in[row * RNN_D + kx] : 0.0f;
                const short h1 = f2bf(w1);
                h8[j] = h1; h8[4 + j] = 0;
                l8[j] = f2bf(w1 - bf2fs(h1));
                l8[4 + j] = 0;
            }
            if (mi == 0) { whiA[4] = h8; wloA[4] = l8; }
            else         { whiB[4] = h8; wloB[4] = l8; }
        }
    }

    // ---- zero-init buffer 0 (h0 = 0); flags = -1 ----
    for (int idx = tid; idx < NB * ROWS; idx += NTHR) {
        (&Hhi[0][0][0])[idx] = 0;
        (&Hlo[0][0][0])[idx] = 0;
    }
    if (tid < NWAVE) hflag[tid] = -1;

    // ---- self B-fragment (kt = wid) starts at h0 = 0 ----
    v8s selfBh = {0, 0, 0, 0, 0, 0, 0, 0};
    v8s selfBl = {0, 0, 0, 0, 0, 0, 0, 0};

    // ---- x prefetch depth 2, named scalars ----
    const float* xrow = xs + (size_t)(b0 + n) * RNN_T * RNN_D;
    float xa0 = xrow[d0], xa1 = xrow[d1], xa2 = xrow[d2], xa3 = xrow[d3];
    float xb0 = xrow[RNN_D + d0], xb1 = xrow[RNN_D + d1];
    float xb2 = xrow[RNN_D + d2], xb3 = xrow[RNN_D + d3];
    __syncthreads();

    // ---- recurrence: SINGLE uniform loop, flag-synced ----
    for (int t = 0; t < RNN_T; t += 2) {
        STEP(0, 1, xa0, xa1, xa2, xa3, t + 2, t);
        STEP(1, 0, xb0, xb1, xb2, xb3, t + 3, t + 1);
    }

    __syncthreads();  // full sync once before epilogue

    // ---- epilogue: out[b][o] = sum_i W_out[o][i] * h_T[i]  (final h in buf 0) ----
    if (wid == 0 && lane < NB * RNN_O) {
        const int nn = lane & 15;
        const int o  = lane >> 4;
        float acc = 0.0f;
        for (int i = 0; i < RNN_H; ++i) {
            const int pos = 32 * (i >> 5) + 8 * ((i >> 2) & 3)
                          + 4 * ((i >> 4) & 1) + (i & 3);
            const float hv = bf2fs(Hhi[0][nn][pos]) + bf2fs(Hlo[0][nn][pos]);
            acc = fmaf(W_out[o * RNN_H + i], hv, acc);
        }
        out[(size_t)(b0 + nn) * RNN_O + o] = acc;
    }
}

extern "C" void kernel_launch(void* const* d_in, const int* in_sizes, int n_in,
                              void* d_out, int out_size, void* d_ws, size_t ws_size,
                              hipStream_t stream) {
    const float* xs    = (const float*)d_in[0];
    const float* W_in  = (const float*)d_in[1];
    const float* W_h   = (const float*)d_in[2];
    const float* W_out = (const float*)d_in[3];
    float* out = (float*)d_out;

    rnn_mfma16_kernel<<<RNN_B / NB, NTHR, 0, stream>>>(xs, W_in, W_h, W_out, out);
}

// Round 17
// 1365.747 us; speedup vs baseline: 1.2871x; 1.2871x over previous
//
#include <hip/hip_runtime.h>
#include <stdint.h>

// RNNModel: h_{t+1} = hardtanh(x_t @ W_in^T + h_t @ W_h^T), out = h_T @ W_out^T
// B=1024 T=2048 D=13 H=128 O=2, fp32 in/out.
//
// Round 17 = r13 (best, 1211us) + SPLIT ACCUMULATOR CHAINS:
//  r10/r13 linear fit: MFMA adds at saturated 19.7cy/MFMA ACROSS waves, with a
//  constant ~1030cy non-MFMA chain. Hypothesis: within ONE wave, r13's 3-way
//  chain interleave (same-chain gap 58cy) is MFMA-dependent-latency bound
//  (L~100-140cy unknown on gfx950) -> each phase ~5L not 291cy issue.
//  Fix (scheduler-proof, via data deps): split each 5-link accumulator chain
//  into two (a: x,kt1,kt3; b: self,kt2) -> 12 chains of <=3 links.
//  Same MFMA count/operands/LDS. Epilogue: pairwise sums (+12 VALU).
//  If latency-bound: ~950-1080us. If null: issue/sync-bound confirmed.
// Base: 4 waves x 2 m-tiles, NB=16, 64 blocks, rotated fragments
// (wA[q] <-> kt=(wid+q)&3), fragment-ordered LDS, cvt_pk epilogue,
// depth-2 x prefetch, lgkm-only fenced barrier, self B-frag forwarding.

#define RNN_B 1024
#define RNN_T 2048
#define RNN_D 13
#define RNN_H 128
#define RNN_O 2

#define NB 16
#define NWAVE 4
#define NTHR (NWAVE * 64)
#define ROWS 136              // shorts per batch row: 128 data + 8 pad (17 quads)

using f32x4 = __attribute__((ext_vector_type(4))) float;
using v8s   = __attribute__((ext_vector_type(8))) short;

__device__ __forceinline__ short f2bf(float f) {           // setup only
    union { float f; uint32_t u; } c; c.f = f;
    uint32_t u = c.u + 0x7fffu + ((c.u >> 16) & 1u);
    return (short)(u >> 16);
}
__device__ __forceinline__ float bf2fs(short s) {
    union { uint32_t u; float f; } c; c.u = ((uint32_t)(uint16_t)s) << 16;
    return c.f;
}
__device__ __forceinline__ float bitf(uint32_t u) {
    union { uint32_t u; float f; } c; c.u = u; return c.f;
}
__device__ __forceinline__ uint32_t cvtpk(float a, float b) {  // [bf16(b)|bf16(a)]
    uint32_t r;
    asm("v_cvt_pk_bf16_f32 %0, %1, %2" : "=v"(r) : "v"(a), "v"(b));
    return r;
}
__device__ __forceinline__ v8s pack4(uint32_t a, uint32_t b, uint32_t c, uint32_t d) {
    union { uint32_t u[4]; v8s s; } z;
    z.u[0] = a; z.u[1] = b; z.u[2] = c; z.u[3] = d; return z.s;
}
__device__ __forceinline__ float clamp1(float v) {
    return __builtin_amdgcn_fmed3f(v, -1.0f, 1.0f);
}

// lgkm-only workgroup barrier (global loads stay in flight across it)
__device__ __forceinline__ void barrier_lgkm() {
    __builtin_amdgcn_sched_barrier(0);
    asm volatile("s_waitcnt lgkmcnt(0)" ::: "memory");
    __builtin_amdgcn_s_barrier();
    asm volatile("" ::: "memory");
    __builtin_amdgcn_sched_barrier(0);
}

#define MFMA(a, b, c) __builtin_amdgcn_mfma_f32_16x16x32_bf16((a), (b), (c), 0, 0, 0)

// One step, uniform for all waves. wA[q]/wB[q] are kt=(wid+q)&3 rotated.
// 12 accumulator chains: {1,2,3}x{a,b}x{A,B}; a: x,kt1,kt3; b: self,kt2.
#define STEP(CUR, NXT, X0, X1, X2, X3, TPF)                                      \
  do {                                                                           \
    /* 1) issue reads for q=1..3 (runtime-uniform offsets, static regs) */       \
    v8s bh1 = *(const v8s*)&Hhi[CUR][n][ktq1 + g8];                              \
    v8s bl1 = *(const v8s*)&Hlo[CUR][n][ktq1 + g8];                              \
    v8s bh2 = *(const v8s*)&Hhi[CUR][n][ktq2 + g8];                              \
    v8s bl2 = *(const v8s*)&Hlo[CUR][n][ktq2 + g8];                              \
    v8s bh3 = *(const v8s*)&Hhi[CUR][n][ktq3 + g8];                              \
    v8s bl3 = *(const v8s*)&Hlo[CUR][n][ktq3 + g8];                              \
    /* 2) x fragments (VALU; overlaps LDS latency) */                            \
    float m0 = X0, m1 = X1, m2 = X2, m3 = X3;                                    \
    if (g == 3) { m1 = 0.0f; m2 = 0.0f; m3 = 0.0f; }                             \
    uint32_t xh01 = cvtpk(m0, m1), xh23 = cvtpk(m2, m3);                         \
    float q0 = m0 - bitf(xh01 << 16);                                            \
    float q1 = m1 - bitf(xh01 & 0xffff0000u);                                    \
    float q2 = m2 - bitf(xh23 << 16);                                            \
    float q3 = m3 - bitf(xh23 & 0xffff0000u);                                    \
    uint32_t xl01 = cvtpk(q0, q1), xl23 = cvtpk(q2, q3);                         \
    v8s xh = pack4(xh01, xh23, 0u, 0u);                                          \
    v8s xl = pack4(xl01, xl23, 0u, 0u);                                          \
    /* 3) reg-only MFMAs: 'a' chains seeded by x, 'b' chains by self */          \
    f32x4 Z = {0.f, 0.f, 0.f, 0.f};                                              \
    f32x4 A1a = MFMA(whiA[4], xh, Z);                                            \
    f32x4 B1a = MFMA(whiB[4], xh, Z);                                            \
    f32x4 A2a = MFMA(whiA[4], xl, Z);                                            \
    f32x4 B2a = MFMA(whiB[4], xl, Z);                                            \
    f32x4 A3a = MFMA(wloA[4], xh, Z);                                            \
    f32x4 B3a = MFMA(wloB[4], xh, Z);                                            \
    f32x4 A1b = MFMA(whiA[0], selfBh, Z);                                        \
    f32x4 B1b = MFMA(whiB[0], selfBh, Z);                                        \
    f32x4 A2b = MFMA(whiA[0], selfBl, Z);                                        \
    f32x4 B2b = MFMA(whiB[0], selfBl, Z);                                        \
    f32x4 A3b = MFMA(wloA[0], selfBh, Z);                                        \
    f32x4 B3b = MFMA(wloB[0], selfBh, Z);                                        \
    /* 4) x prefetch two steps ahead (stays in vmcnt across barriers) */         \
    if ((TPF) < RNN_T) {                                                         \
      const float* xp = xrow + (size_t)(TPF) * RNN_D;                            \
      X0 = xp[d0]; X1 = xp[d1]; X2 = xp[d2]; X3 = xp[d3];                        \
    }                                                                            \
    /* 5) LDS-dependent MFMAs: kt1,kt3 -> 'a' chains, kt2 -> 'b' chains */       \
    A1a = MFMA(whiA[1], bh1, A1a);                                               \
    B1a = MFMA(whiB[1], bh1, B1a);                                               \
    A2a = MFMA(whiA[1], bl1, A2a);                                               \
    B2a = MFMA(whiB[1], bl1, B2a);                                               \
    A3a = MFMA(wloA[1], bh1, A3a);                                               \
    B3a = MFMA(wloB[1], bh1, B3a);                                               \
    A1b = MFMA(whiA[2], bh2, A1b);                                               \
    B1b = MFMA(whiB[2], bh2, B1b);                                               \
    A2b = MFMA(whiA[2], bl2, A2b);                                               \
    B2b = MFMA(whiB[2], bl2, B2b);                                               \
    A3b = MFMA(wloA[2], bh2, A3b);                                               \
    B3b = MFMA(wloB[2], bh2, B3b);                                               \
    A1a = MFMA(whiA[3], bh3, A1a);                                               \
    B1a = MFMA(whiB[3], bh3, B1a);                                               \
    A2a = MFMA(whiA[3], bl3, A2a);                                               \
    B2a = MFMA(whiB[3], bl3, B2a);                                               \
    A3a = MFMA(wloA[3], bh3, A3a);                                               \
    B3a = MFMA(wloB[3], bh3, B3a);                                               \
    /* 6) A epilogue: pairwise chain sums, clip, split, b64 write */             \
    float v0 = clamp1((A1a[0] + A1b[0]) + (A2a[0] + A2b[0]) + (A3a[0] + A3b[0]));\
    float v1 = clamp1((A1a[1] + A1b[1]) + (A2a[1] + A2b[1]) + (A3a[1] + A3b[1]));\
    float v2 = clamp1((A1a[2] + A1b[2]) + (A2a[2] + A2b[2]) + (A3a[2] + A3b[2]));\
    float v3 = clamp1((A1a[3] + A1b[3]) + (A2a[3] + A2b[3]) + (A3a[3] + A3b[3]));\
    uint32_t h01A = cvtpk(v0, v1), h23A = cvtpk(v2, v3);                         \
    float p0 = v0 - bitf(h01A << 16);                                            \
    float p1 = v1 - bitf(h01A & 0xffff0000u);                                    \
    float p2 = v2 - bitf(h23A << 16);                                            \
    float p3 = v3 - bitf(h23A & 0xffff0000u);                                    \
    uint32_t l01A = cvtpk(p0, p1), l23A = cvtpk(p2, p3);                         \
    {                                                                            \
      int2 wv; wv.x = (int)h01A; wv.y = (int)h23A;                               \
      *(int2*)&Hhi[NXT][n][wbase + g8] = wv;                                     \
      wv.x = (int)l01A; wv.y = (int)l23A;                                        \
      *(int2*)&Hlo[NXT][n][wbase + g8] = wv;                                     \
    }                                                                            \
    /* 7) B epilogue; combined fragments = next selfB; b64 writes */             \
    {                                                                            \
      float w0 = clamp1((B1a[0]+B1b[0]) + (B2a[0]+B2b[0]) + (B3a[0]+B3b[0]));    \
      float w1 = clamp1((B1a[1]+B1b[1]) + (B2a[1]+B2b[1]) + (B3a[1]+B3b[1]));    \
      float w2 = clamp1((B1a[2]+B1b[2]) + (B2a[2]+B2b[2]) + (B3a[2]+B3b[2]));    \
      float w3 = clamp1((B1a[3]+B1b[3]) + (B2a[3]+B2b[3]) + (B3a[3]+B3b[3]));    \
      uint32_t h01B = cvtpk(w0, w1), h23B = cvtpk(w2, w3);                       \
      float r0 = w0 - bitf(h01B << 16);                                          \
      float r1 = w1 - bitf(h01B & 0xffff0000u);                                  \
      float r2 = w2 - bitf(h23B << 16);                                          \
      float r3 = w3 - bitf(h23B & 0xffff0000u);                                  \
      uint32_t l01B = cvtpk(r0, r1), l23B = cvtpk(r2, r3);                       \
      selfBh = pack4(h01A, h23A, h01B, h23B);                                    \
      selfBl = pack4(l01A, l23A, l01B, l23B);                                    \
      int2 wv; wv.x = (int)h01B; wv.y = (int)h23B;                               \
      *(int2*)&Hhi[NXT][n][wbase + g8 + 4] = wv;                                 \
      wv.x = (int)l01B; wv.y = (int)l23B;                                        \
      *(int2*)&Hlo[NXT][n][wbase + g8 + 4] = wv;                                 \
    }                                                                            \
    barrier_lgkm();                                                              \
  } while (0)

__global__ __launch_bounds__(NTHR, 1) void rnn_mfma17_kernel(
    const float* __restrict__ xs,     // [B, T, D]
    const float* __restrict__ W_in,   // [H, D]
    const float* __restrict__ W_h,    // [H, H]
    const float* __restrict__ W_out,  // [O, H]
    float* __restrict__ out)          // [B, O]
{
    __shared__ __align__(16) short Hhi[2][NB][ROWS];
    __shared__ __align__(16) short Hlo[2][NB][ROWS];

    const int tid  = threadIdx.x;
    const int lane = tid & 63;
    const int wid  = tid >> 6;       // wave 0..3; self kt = wid
    const int n    = lane & 15;      // batch col / A-row within tile
    const int g    = lane >> 4;      // k-group 0..3
    const int g8   = g * 8;
    const int wbase = 32 * wid;      // write base: pos = 32*wid + 8g + 4*mi
    const int b0   = blockIdx.x * NB;

    // rotated kt short-offsets for q=1..3 (runtime-uniform, used in addresses)
    const int ktq1 = ((wid + 1) & 3) * 32;
    const int ktq2 = ((wid + 2) & 3) * 32;
    const int ktq3 = ((wid + 3) & 3) * 32;

    // clamped x element indices for this lane (d = 4g+j, clamped into [0,12])
    const int d0 = (4 * g + 0 > 12) ? 12 : 4 * g + 0;
    const int d1 = (4 * g + 1 > 12) ? 12 : 4 * g + 1;
    const int d2 = (4 * g + 2 > 12) ? 12 : 4 * g + 2;
    const int d3 = (4 * g + 3 > 12) ? 12 : 4 * g + 3;

    // ---- A fragments, ROTATED: wA[q] <-> kt=(wid+q)&3; index 4 = x tile ----
    v8s whiA[5], wloA[5], whiB[5], wloB[5];
    #pragma unroll
    for (int mi = 0; mi < 2; ++mi) {
        const int row = 16 * (wid * 2 + mi) + n;
        #pragma unroll
        for (int q = 0; q < 4; ++q) {
            const int kt = (wid + q) & 3;          // runtime; addresses only
            v8s h8, l8;
            #pragma unroll
            for (int j = 0; j < 4; ++j) {
                const float w1 = W_h[row * RNN_H + 32 * kt + 4 * g + j];
                const float w2 = W_h[row * RNN_H + 32 * kt + 16 + 4 * g + j];
                const short h1 = f2bf(w1);
                const short h2 = f2bf(w2);
                h8[j] = h1; h8[4 + j] = h2;
                l8[j] = f2bf(w1 - bf2fs(h1));
                l8[4 + j] = f2bf(w2 - bf2fs(h2));
            }
            if (mi == 0) { whiA[q] = h8; wloA[q] = l8; }
            else         { whiB[q] = h8; wloB[q] = l8; }
        }
        {   // x tile (index 4)
            v8s h8, l8;
            #pragma unroll
            for (int j = 0; j < 4; ++j) {
                const int kx = 4 * g + j;
                const float w1 = (kx < RNN_D) ? W_in[row * RNN_D + kx] : 0.0f;
                const short h1 = f2bf(w1);
                h8[j] = h1; h8[4 + j] = 0;
                l8[j] = f2bf(w1 - bf2fs(h1));
                l8[4 + j] = 0;
            }
            if (mi == 0) { whiA[4] = h8; wloA[4] = l8; }
            else         { whiB[4] = h8; wloB[4] = l8; }
        }
    }

    // ---- zero-init buffer 0 (h0 = 0) ----
    for (int idx = tid; idx < NB * ROWS; idx += NTHR) {
        (&Hhi[0][0][0])[idx] = 0;
        (&Hlo[0][0][0])[idx] = 0;
    }

    // ---- self B-fragment (kt = wid) starts at h0 = 0 ----
    v8s selfBh = {0, 0, 0, 0, 0, 0, 0, 0};
    v8s selfBl = {0, 0, 0, 0, 0, 0, 0, 0};

    // ---- x prefetch depth 2, named scalars ----
    const float* xrow = xs + (size_t)(b0 + n) * RNN_T * RNN_D;
    float xa0 = xrow[d0], xa1 = xrow[d1], xa2 = xrow[d2], xa3 = xrow[d3];
    float xb0 = xrow[RNN_D + d0], xb1 = xrow[RNN_D + d1];
    float xb2 = xrow[RNN_D + d2], xb3 = xrow[RNN_D + d3];
    __syncthreads();

    // ---- recurrence: SINGLE uniform loop for all waves ----
    for (int t = 0; t < RNN_T; t += 2) {
        STEP(0, 1, xa0, xa1, xa2, xa3, t + 2);
        STEP(1, 0, xb0, xb1, xb2, xb3, t + 3);
    }

    __syncthreads();  // full sync once before epilogue

    // ---- epilogue: out[b][o] = sum_i W_out[o][i] * h_T[i]  (final h in buf 0) ----
    if (wid == 0 && lane < NB * RNN_O) {
        const int nn = lane & 15;
        const int o  = lane >> 4;
        float acc = 0.0f;
        for (int i = 0; i < RNN_H; ++i) {
            const int pos = 32 * (i >> 5) + 8 * ((i >> 2) & 3)
                          + 4 * ((i >> 4) & 1) + (i & 3);
            const float hv = bf2fs(Hhi[0][nn][pos]) + bf2fs(Hlo[0][nn][pos]);
            acc = fmaf(W_out[o * RNN_H + i], hv, acc);
        }
        out[(size_t)(b0 + nn) * RNN_O + o] = acc;
    }
}

extern "C" void kernel_launch(void* const* d_in, const int* in_sizes, int n_in,
                              void* d_out, int out_size, void* d_ws, size_t ws_size,
                              hipStream_t stream) {
    const float* xs    = (const float*)d_in[0];
    const float* W_in  = (const float*)d_in[1];
    const float* W_h   = (const float*)d_in[2];
    const float* W_out = (const float*)d_in[3];
    float* out = (float*)d_out;

    rnn_mfma17_kernel<<<RNN_B / NB, NTHR, 0, stream>>>(xs, W_in, W_h, W_out, out);
}

// Round 18
// 1216.935 us; speedup vs baseline: 1.4445x; 1.1223x over previous
//
#include <hip/hip_runtime.h>
#include <stdint.h>

// RNNModel: h_{t+1} = hardtanh(x_t @ W_in^T + h_t @ W_h^T), out = h_T @ W_out^T
// B=1024 T=2048 D=13 H=128 O=2, fp32 in/out.
//
// Round 18 = r13 (best, 1211us) + XOR-swizzled LDS + merged b128 h-write:
//  - LDS rows shrink 136->128 shorts (16 quads, power of 2). Physical quad =
//    logical quad ^ (n&15), logical quad = 4*kt+g (read) / 4*wid+g (write).
//    Kills the systematic n<->n+8 bank collision (any 16B-aligned row stride
//    has 8*stride%32dw==0) -> read burst drains at the inherent 8 phases.
//  - h written as ONE ds_write_b128 (the selfB value) per buffer (r14's merge).
//  - All addresses are per-lane loop constants (off1..3, offw).
//  Arithmetic bit-identical to r13 (absmax must stay 0.0078125).
// Base: 4 waves x 2 m-tiles, NB=16, 64 blocks, rotated fragments
// (wA[q] <-> kt=(wid+q)&3), cvt_pk epilogue, depth-2 x prefetch,
// lgkm-only fenced barrier, self B-fragment register forwarding.

#define RNN_B 1024
#define RNN_T 2048
#define RNN_D 13
#define RNN_H 128
#define RNN_O 2

#define NB 16
#define NWAVE 4
#define NTHR (NWAVE * 64)

using f32x4 = __attribute__((ext_vector_type(4))) float;
using v8s   = __attribute__((ext_vector_type(8))) short;

__device__ __forceinline__ short f2bf(float f) {           // setup only
    union { float f; uint32_t u; } c; c.f = f;
    uint32_t u = c.u + 0x7fffu + ((c.u >> 16) & 1u);
    return (short)(u >> 16);
}
__device__ __forceinline__ float bf2fs(short s) {
    union { uint32_t u; float f; } c; c.u = ((uint32_t)(uint16_t)s) << 16;
    return c.f;
}
__device__ __forceinline__ float bitf(uint32_t u) {
    union { uint32_t u; float f; } c; c.u = u; return c.f;
}
__device__ __forceinline__ uint32_t cvtpk(float a, float b) {  // [bf16(b)|bf16(a)]
    uint32_t r;
    asm("v_cvt_pk_bf16_f32 %0, %1, %2" : "=v"(r) : "v"(a), "v"(b));
    return r;
}
__device__ __forceinline__ v8s pack4(uint32_t a, uint32_t b, uint32_t c, uint32_t d) {
    union { uint32_t u[4]; v8s s; } z;
    z.u[0] = a; z.u[1] = b; z.u[2] = c; z.u[3] = d; return z.s;
}
__device__ __forceinline__ float clamp1(float v) {
    return __builtin_amdgcn_fmed3f(v, -1.0f, 1.0f);
}

// lgkm-only workgroup barrier (global loads stay in flight across it)
__device__ __forceinline__ void barrier_lgkm() {
    __builtin_amdgcn_sched_barrier(0);
    asm volatile("s_waitcnt lgkmcnt(0)" ::: "memory");
    __builtin_amdgcn_s_barrier();
    asm volatile("" ::: "memory");
    __builtin_amdgcn_sched_barrier(0);
}

#define MFMA(a, b, c) __builtin_amdgcn_mfma_f32_16x16x32_bf16((a), (b), (c), 0, 0, 0)

// One step, uniform for all waves. wA[q]/wB[q] are kt=(wid+q)&3 rotated.
// off1..3 / offw are swizzled per-lane short offsets (loop constants).
#define STEP(CUR, NXT, X0, X1, X2, X3, TPF)                                      \
  do {                                                                           \
    /* 1) issue reads for q=1..3 (swizzled, conflict-minimal) */                 \
    v8s bh1 = *(const v8s*)&Hhi[CUR][off1];                                      \
    v8s bl1 = *(const v8s*)&Hlo[CUR][off1];                                      \
    v8s bh2 = *(const v8s*)&Hhi[CUR][off2];                                      \
    v8s bl2 = *(const v8s*)&Hlo[CUR][off2];                                      \
    v8s bh3 = *(const v8s*)&Hhi[CUR][off3];                                      \
    v8s bl3 = *(const v8s*)&Hlo[CUR][off3];                                      \
    /* 2) x fragments (VALU; overlaps LDS latency) */                            \
    float m0 = X0, m1 = X1, m2 = X2, m3 = X3;                                    \
    if (g == 3) { m1 = 0.0f; m2 = 0.0f; m3 = 0.0f; }                             \
    uint32_t xh01 = cvtpk(m0, m1), xh23 = cvtpk(m2, m3);                         \
    float q0 = m0 - bitf(xh01 << 16);                                            \
    float q1 = m1 - bitf(xh01 & 0xffff0000u);                                    \
    float q2 = m2 - bitf(xh23 << 16);                                            \
    float q3 = m3 - bitf(xh23 & 0xffff0000u);                                    \
    uint32_t xl01 = cvtpk(q0, q1), xl23 = cvtpk(q2, q3);                         \
    v8s xh = pack4(xh01, xh23, 0u, 0u);                                          \
    v8s xl = pack4(xl01, xl23, 0u, 0u);                                          \
    /* 3) A-tile MFMAs: x + self first (reg-only), then q1..q3 */                \
    f32x4 Z = {0.f, 0.f, 0.f, 0.f};                                              \
    f32x4 A1 = MFMA(whiA[4], xh, Z);                                             \
    f32x4 A2 = MFMA(whiA[4], xl, Z);                                             \
    f32x4 A3 = MFMA(wloA[4], xh, Z);                                             \
    A1 = MFMA(whiA[0], selfBh, A1);                                              \
    A2 = MFMA(whiA[0], selfBl, A2);                                              \
    A3 = MFMA(wloA[0], selfBh, A3);                                              \
    /* 4) x prefetch two steps ahead (stays in vmcnt across barriers) */         \
    if ((TPF) < RNN_T) {                                                         \
      const float* xp = xrow + (size_t)(TPF) * RNN_D;                            \
      X0 = xp[d0]; X1 = xp[d1]; X2 = xp[d2]; X3 = xp[d3];                        \
    }                                                                            \
    A1 = MFMA(whiA[1], bh1, A1);                                                 \
    A2 = MFMA(whiA[1], bl1, A2);                                                 \
    A3 = MFMA(wloA[1], bh1, A3);                                                 \
    A1 = MFMA(whiA[2], bh2, A1);                                                 \
    A2 = MFMA(whiA[2], bl2, A2);                                                 \
    A3 = MFMA(wloA[2], bh2, A3);                                                 \
    A1 = MFMA(whiA[3], bh3, A1);                                                 \
    A2 = MFMA(whiA[3], bl3, A2);                                                 \
    A3 = MFMA(wloA[3], bh3, A3);                                                 \
    /* 5) B-tile x+self MFMAs, then q1..q3, A epilogue interleaved */            \
    f32x4 B1 = MFMA(whiB[4], xh, Z);                                             \
    f32x4 B2 = MFMA(whiB[4], xl, Z);                                             \
    f32x4 B3 = MFMA(wloB[4], xh, Z);                                             \
    B1 = MFMA(whiB[0], selfBh, B1);                                              \
    B2 = MFMA(whiB[0], selfBl, B2);                                              \
    B3 = MFMA(wloB[0], selfBh, B3);                                              \
    float v0 = clamp1(A1[0] + A2[0] + A3[0]);                                    \
    float v1 = clamp1(A1[1] + A2[1] + A3[1]);                                    \
    float v2 = clamp1(A1[2] + A2[2] + A3[2]);                                    \
    float v3 = clamp1(A1[3] + A2[3] + A3[3]);                                    \
    B1 = MFMA(whiB[1], bh1, B1);                                                 \
    B2 = MFMA(whiB[1], bl1, B2);                                                 \
    B3 = MFMA(wloB[1], bh1, B3);                                                 \
    uint32_t h01A = cvtpk(v0, v1), h23A = cvtpk(v2, v3);                         \
    float p0 = v0 - bitf(h01A << 16);                                            \
    float p1 = v1 - bitf(h01A & 0xffff0000u);                                    \
    float p2 = v2 - bitf(h23A << 16);                                            \
    float p3 = v3 - bitf(h23A & 0xffff0000u);                                    \
    B1 = MFMA(whiB[2], bh2, B1);                                                 \
    B2 = MFMA(whiB[2], bl2, B2);                                                 \
    B3 = MFMA(wloB[2], bh2, B3);                                                 \
    uint32_t l01A = cvtpk(p0, p1), l23A = cvtpk(p2, p3);                         \
    B1 = MFMA(whiB[3], bh3, B1);                                                 \
    B2 = MFMA(whiB[3], bl3, B2);                                                 \
    B3 = MFMA(wloB[3], bh3, B3);                                                 \
    /* 6) B epilogue; combined fragments = next selfB; ONE b128 write each */    \
    {                                                                            \
      float w0 = clamp1(B1[0] + B2[0] + B3[0]);                                  \
      float w1 = clamp1(B1[1] + B2[1] + B3[1]);                                  \
      float w2 = clamp1(B1[2] + B2[2] + B3[2]);                                  \
      float w3 = clamp1(B1[3] + B2[3] + B3[3]);                                  \
      uint32_t h01B = cvtpk(w0, w1), h23B = cvtpk(w2, w3);                       \
      float r0 = w0 - bitf(h01B << 16);                                          \
      float r1 = w1 - bitf(h01B & 0xffff0000u);                                  \
      float r2 = w2 - bitf(h23B << 16);                                          \
      float r3 = w3 - bitf(h23B & 0xffff0000u);                                  \
      uint32_t l01B = cvtpk(r0, r1), l23B = cvtpk(r2, r3);                       \
      selfBh = pack4(h01A, h23A, h01B, h23B);                                    \
      selfBl = pack4(l01A, l23A, l01B, l23B);                                    \
      *(v8s*)&Hhi[NXT][offw] = selfBh;                                           \
      *(v8s*)&Hlo[NXT][offw] = selfBl;                                           \
    }                                                                            \
    barrier_lgkm();                                                              \
  } while (0)

__global__ __launch_bounds__(NTHR, 1) void rnn_mfma18_kernel(
    const float* __restrict__ xs,     // [B, T, D]
    const float* __restrict__ W_in,   // [H, D]
    const float* __restrict__ W_h,    // [H, H]
    const float* __restrict__ W_out,  // [O, H]
    float* __restrict__ out)          // [B, O]
{
    __shared__ __align__(16) short Hhi[2][NB * 128];
    __shared__ __align__(16) short Hlo[2][NB * 128];

    const int tid  = threadIdx.x;
    const int lane = tid & 63;
    const int wid  = tid >> 6;       // wave 0..3; self kt = wid
    const int n    = lane & 15;      // batch col / A-row within tile
    const int g    = lane >> 4;      // k-group 0..3
    const int b0   = blockIdx.x * NB;

    // swizzled per-lane short offsets: phys quad = (4*kt + g) ^ n
    const int off1 = n * 128 + (((((wid + 1) & 3) << 2) + g) ^ n) * 8;
    const int off2 = n * 128 + (((((wid + 2) & 3) << 2) + g) ^ n) * 8;
    const int off3 = n * 128 + (((((wid + 3) & 3) << 2) + g) ^ n) * 8;
    const int offw = n * 128 + (((wid << 2) + g) ^ n) * 8;

    // clamped x element indices for this lane (d = 4g+j, clamped into [0,12])
    const int d0 = (4 * g + 0 > 12) ? 12 : 4 * g + 0;
    const int d1 = (4 * g + 1 > 12) ? 12 : 4 * g + 1;
    const int d2 = (4 * g + 2 > 12) ? 12 : 4 * g + 2;
    const int d3 = (4 * g + 3 > 12) ? 12 : 4 * g + 3;

    // ---- A fragments, ROTATED: wA[q] <-> kt=(wid+q)&3; index 4 = x tile ----
    v8s whiA[5], wloA[5], whiB[5], wloB[5];
    #pragma unroll
    for (int mi = 0; mi < 2; ++mi) {
        const int row = 16 * (wid * 2 + mi) + n;
        #pragma unroll
        for (int q = 0; q < 4; ++q) {
            const int kt = (wid + q) & 3;          // runtime; addresses only
            v8s h8, l8;
            #pragma unroll
            for (int j = 0; j < 4; ++j) {
                const float w1 = W_h[row * RNN_H + 32 * kt + 4 * g + j];
                const float w2 = W_h[row * RNN_H + 32 * kt + 16 + 4 * g + j];
                const short h1 = f2bf(w1);
                const short h2 = f2bf(w2);
                h8[j] = h1; h8[4 + j] = h2;
                l8[j] = f2bf(w1 - bf2fs(h1));
                l8[4 + j] = f2bf(w2 - bf2fs(h2));
            }
            if (mi == 0) { whiA[q] = h8; wloA[q] = l8; }
            else         { whiB[q] = h8; wloB[q] = l8; }
        }
        {   // x tile (index 4)
            v8s h8, l8;
            #pragma unroll
            for (int j = 0; j < 4; ++j) {
                const int kx = 4 * g + j;
                const float w1 = (kx < RNN_D) ? W_in[row * RNN_D + kx] : 0.0f;
                const short h1 = f2bf(w1);
                h8[j] = h1; h8[4 + j] = 0;
                l8[j] = f2bf(w1 - bf2fs(h1));
                l8[4 + j] = 0;
            }
            if (mi == 0) { whiA[4] = h8; wloA[4] = l8; }
            else         { whiB[4] = h8; wloB[4] = l8; }
        }
    }

    // ---- zero-init buffer 0 (h0 = 0) ----
    for (int idx = tid; idx < NB * 128; idx += NTHR) {
        Hhi[0][idx] = 0;
        Hlo[0][idx] = 0;
    }

    // ---- self B-fragment (kt = wid) starts at h0 = 0 ----
    v8s selfBh = {0, 0, 0, 0, 0, 0, 0, 0};
    v8s selfBl = {0, 0, 0, 0, 0, 0, 0, 0};

    // ---- x prefetch depth 2, named scalars ----
    const float* xrow = xs + (size_t)(b0 + n) * RNN_T * RNN_D;
    float xa0 = xrow[d0], xa1 = xrow[d1], xa2 = xrow[d2], xa3 = xrow[d3];
    float xb0 = xrow[RNN_D + d0], xb1 = xrow[RNN_D + d1];
    float xb2 = xrow[RNN_D + d2], xb3 = xrow[RNN_D + d3];
    __syncthreads();

    // ---- recurrence: SINGLE uniform loop for all waves ----
    for (int t = 0; t < RNN_T; t += 2) {
        STEP(0, 1, xa0, xa1, xa2, xa3, t + 2);
        STEP(1, 0, xb0, xb1, xb2, xb3, t + 3);
    }

    __syncthreads();  // full sync once before epilogue

    // ---- epilogue: out[b][o] = sum_i W_out[o][i] * h_T[i]  (final h in buf 0) ----
    if (wid == 0 && lane < NB * RNN_O) {
        const int nn = lane & 15;
        const int o  = lane >> 4;
        float acc = 0.0f;
        for (int i = 0; i < RNN_H; ++i) {
            const int pos = 32 * (i >> 5) + 8 * ((i >> 2) & 3)
                          + 4 * ((i >> 4) & 1) + (i & 3);
            const int adr = nn * 128 + ((pos >> 3) ^ nn) * 8 + (pos & 7);
            const float hv = bf2fs(Hhi[0][adr]) + bf2fs(Hlo[0][adr]);
            acc = fmaf(W_out[o * RNN_H + i], hv, acc);
        }
        out[(size_t)(b0 + nn) * RNN_O + o] = acc;
    }
}

extern "C" void kernel_launch(void* const* d_in, const int* in_sizes, int n_in,
                              void* d_out, int out_size, void* d_ws, size_t ws_size,
                              hipStream_t stream) {
    const float* xs    = (const float*)d_in[0];
    const float* W_in  = (const float*)d_in[1];
    const float* W_h   = (const float*)d_in[2];
    const float* W_out = (const float*)d_in[3];
    float* out = (float*)d_out;

    rnn_mfma18_kernel<<<RNN_B / NB, NTHR, 0, stream>>>(xs, W_in, W_h, W_out, out);
}